// Round 4
// baseline (118.388 us; speedup 1.0000x reference)
//
#include <hip/hip_runtime.h>
#include <hip/hip_bf16.h>

typedef unsigned short u16;
typedef unsigned int   u32;
typedef __attribute__((ext_vector_type(8))) short bf16x8;
typedef __attribute__((ext_vector_type(4))) float f32x4;

#define NC  256
#define NHW 4096

// ---- LDS layout (bytes) ----
// Region A (32KB): x-tile bf16 token-major -> q^T bf16 token-major -> per-wave output transpose
#define OFF_XZT 0
#define OFF_AC  32768    // u16[64][64] XOR-swizzled: A (per-iter, wave-private rows) then C
#define OFF_ST  40960    // f32[64][4]  ||q||^2 partials per wave
#define OFF_RI  41984    // f32[64]     rinv0 per token
#define SMEM_SZ 42240

__device__ __forceinline__ u16 f2bf_rne(float f) {   // manual RNE (prep path)
  u32 u = __float_as_uint(f);
  return (u16)((u + 0x7FFFu + ((u >> 16) & 1u)) >> 16);
}
__device__ __forceinline__ u16 f2bf(float f) {       // hot path (compiler cvt)
  __hip_bfloat16 h = __float2bfloat16(f);
  return *reinterpret_cast<u16*>(&h);
}
__device__ __forceinline__ u32 pack2(float a, float b) {
  return (u32)f2bf(a) | ((u32)f2bf(b) << 16);
}

// ---- prep: Wq/Wout -> bf16; mem_norm bf16; G = mn@mn^T bf16; WM = Wout@mn^T bf16 ----
__global__ void hop_prep(const float* __restrict__ wq_f, const float* __restrict__ wo_f,
                         const float* __restrict__ memb,
                         u16* __restrict__ wq_b, u16* __restrict__ wo_b,
                         u16* __restrict__ mem_b, u16* __restrict__ G_b,
                         u16* __restrict__ WM_b) {
  int blk = blockIdx.x, tid = threadIdx.x;
  if (blk < 32) {
    int base = blk * 2048;
    #pragma unroll
    for (int i = 0; i < 8; ++i) wq_b[base + tid + 256*i] = f2bf_rne(wq_f[base + tid + 256*i]);
    return;
  }
  if (blk < 64) {
    int base = (blk - 32) * 2048;
    #pragma unroll
    for (int i = 0; i < 8; ++i) wo_b[base + tid + 256*i] = f2bf_rne(wo_f[base + tid + 256*i]);
    return;
  }
  if (blk == 64) {
    int m = tid >> 2, part = tid & 3;
    float s = 0.f;
    for (int j = 0; j < 64; ++j) { float v = memb[m*NC + part*64 + j]; s += v*v; }
    s += __shfl_xor(s, 1);
    s += __shfl_xor(s, 2);
    float inv = 1.0f / fmaxf(sqrtf(s), 1e-12f);
    for (int j = 0; j < 64; ++j) {
      int c = part*64 + j;
      mem_b[m*NC + c] = f2bf_rne(memb[m*NC + c] * inv);
    }
    return;
  }
  // blk 65: G;  blk 66..97: WM (8 o-rows each)
  __shared__ float sm[64][257];
  __shared__ float rn[64];
  for (int i = tid; i < 64*256; i += 256) { sm[i >> 8][i & 255] = memb[i]; }
  __syncthreads();
  if (tid < 64) {
    float s = 0.f;
    for (int c = 0; c < 256; ++c) { float v = sm[tid][c]; s += v*v; }
    rn[tid] = 1.0f / fmaxf(sqrtf(s), 1e-12f);
  }
  __syncthreads();
  if (blk == 65) {
    for (int i = tid; i < 4096; i += 256) {
      int m = i >> 6, mp = i & 63;
      float s = 0.f;
      for (int c = 0; c < 256; ++c) s += sm[m][c] * sm[mp][c];
      G_b[i] = f2bf_rne(s * rn[m] * rn[mp]);
    }
  } else {
    int o0 = (blk - 66) * 8;
    for (int i = tid; i < 512; i += 256) {
      int ol = i >> 6, m = i & 63;
      const float* wrow = wo_f + (size_t)(o0 + ol) * NC;
      float s = 0.f;
      for (int c = 0; c < 256; ++c) s += wrow[c] * sm[m][c];
      WM_b[(size_t)(o0 + ol) * 64 + m] = f2bf_rne(s * rn[m]);
    }
  }
}

// ---- fused main kernel: block = 64 tokens, 4 waves ----
__global__ __launch_bounds__(256, 3) void hop_main(
    const float* __restrict__ x, const float* __restrict__ bq,
    const float* __restrict__ bout, const u16* __restrict__ wq,
    const u16* __restrict__ wout, const u16* __restrict__ gmem,
    const u16* __restrict__ Gb, const u16* __restrict__ WMb,
    float* __restrict__ out) {
  __shared__ __align__(16) char smem[SMEM_SZ];
  float* StatR = (float*)(smem + OFF_ST);   // [64][4]
  float* RinvL = (float*)(smem + OFF_RI);   // [64]

  const int tid = threadIdx.x;
  const int w  = tid >> 6;
  const int l  = tid & 63;
  const int lg = l >> 4;
  const int ll = l & 15;
  const int swz = (ll & 7) << 4;            // XOR byte-swizzle key for rows ≡ ll (mod 8)

  const int bimg = blockIdx.x >> 6;         // 64 blocks per image
  const int t0   = (blockIdx.x & 63) * 64;
  const float* xb = x   + (size_t)bimg * NC * NHW + t0;
  float*       ob = out + (size_t)bimg * NC * NHW + t0;

  // ======= stage x-tile -> region A: bf16 token-major [t][c], XOR-swizzled =======
  // thread loads float4 pairs (rows 2cp, 2cp+1; 4 tokens), writes 4 u32 (c-pairs).
  {
    const int tq = tid & 15;          // token quad: t = 4tq..4tq+3
    const int cb = tid >> 4;          // 0..15
    #pragma unroll
    for (int j = 0; j < 8; ++j) {
      int cp = cb + 16*j;             // c-pair: c = 2cp, 2cp+1
      const float* r0 = xb + (size_t)(2*cp) * NHW + 4*tq;
      float4 a = *(const float4*)r0;
      float4 b = *(const float4*)(r0 + NHW);
      #pragma unroll
      for (int i = 0; i < 4; ++i) {
        int t = 4*tq + i;
        *(u32*)(smem + OFF_XZT + (t << 9) + (((u32)(cp << 2)) ^ (u32)((t & 7) << 4)))
            = pack2((&a.x)[i], (&b.x)[i]);
      }
    }
  }
  float bq_r[4], bo_r[4];
  #pragma unroll
  for (int ni = 0; ni < 4; ++ni) {
    bq_r[ni] = bq[64*w + 16*ni + ll];   // kept for symmetry (bias applied via f32x4 below)
    bo_r[ni] = bout[64*w + 16*ni + ll];
  }
  __syncthreads();   // barrier 1: x-tile ready

  // ======= GEMM1: q^T[o][t] = Wq[o][:]·x[:][t] + bq  (wave w owns o in [64w,64w+64)) =======
  f32x4 acc[4][4];   // [oi][ti]: o = 64w+16oi+4lg+r, t = 16ti+ll
  #pragma unroll
  for (int oi = 0; oi < 4; ++oi)
    #pragma unroll
    for (int ti = 0; ti < 4; ++ti) acc[oi][ti] = (f32x4){0.f,0.f,0.f,0.f};
  {
    #pragma unroll
    for (int kk = 0; kk < 8; ++kk) {
      bf16x8 nf[4];                          // B-frag: x[c=32kk+8lg+j][t=16ti+ll] from LDS
      #pragma unroll
      for (int ti = 0; ti < 4; ++ti) {
        int row = 16*ti + ll;
        nf[ti] = *(const bf16x8*)(smem + OFF_XZT + (row << 9)
                                  + ((u32)(64*kk + 16*lg) ^ (u32)((row & 7) << 4)));
      }
      bf16x8 mf[4];                          // A-frag: Wq rows (global, L1-hot)
      #pragma unroll
      for (int oi = 0; oi < 4; ++oi)
        mf[oi] = *(const bf16x8*)(wq + (size_t)(64*w + 16*oi + ll) * NC + 32*kk + 8*lg);
      #pragma unroll
      for (int oi = 0; oi < 4; ++oi)
        #pragma unroll
        for (int ti = 0; ti < 4; ++ti)
          acc[oi][ti] = __builtin_amdgcn_mfma_f32_16x16x32_bf16(mf[oi], nf[ti], acc[oi][ti], 0, 0, 0);
    }
  }
  #pragma unroll
  for (int oi = 0; oi < 4; ++oi) {
    f32x4 bv = *(const f32x4*)&bq[64*w + 16*oi + 4*lg];
    #pragma unroll
    for (int ti = 0; ti < 4; ++ti)
      #pragma unroll
      for (int r = 0; r < 4; ++r) acc[oi][ti][r] += bv[r];
  }

  // ---- ||q||^2 partials -> StatR ----
  #pragma unroll
  for (int ti = 0; ti < 4; ++ti) {
    float v = 0.f;
    #pragma unroll
    for (int oi = 0; oi < 4; ++oi)
      #pragma unroll
      for (int r = 0; r < 4; ++r) { float e = acc[oi][ti][r]; v += e*e; }
    v += __shfl_xor(v, 16);
    v += __shfl_xor(v, 32);
    if (lg == 0) StatR[(16*ti + ll)*4 + w] = v;
  }
  __syncthreads();   // barrier 2: all x-tile reads done; StatR ready

  // ---- q^T -> region A (overwrite), bf16 XOR-swizzled, row = token ----
  #pragma unroll
  for (int oi = 0; oi < 4; ++oi)
    #pragma unroll
    for (int ti = 0; ti < 4; ++ti) {
      int row = 16*ti + ll;
      int colb = (64*w + 16*oi + 4*lg) << 1;
      uint2 v; v.x = pack2(acc[oi][ti][0], acc[oi][ti][1]);
               v.y = pack2(acc[oi][ti][2], acc[oi][ti][3]);
      *(uint2*)(smem + OFF_XZT + (row << 9) + ((u32)colb ^ swz)) = v;
    }
  __syncthreads();   // barrier 3: q^T ready

  // ---- rinv0 for this wave's own token (t = 16w+ll) ----
  const int t_own = 16*w + ll;
  float rinv0;
  {
    f32x4 p = *(const f32x4*)&StatR[t_own * 4];
    rinv0 = 1.0f / fmaxf(sqrtf(p[0] + p[1] + p[2] + p[3]), 1e-12f);
    if (lg == 0) RinvL[t_own] = rinv0;
  }

  // ======= P0 = rinv0 * (q @ mem^T), per-wave (16 tokens) =======
  const char* xrow = smem + OFF_XZT + (t_own << 9);
  f32x4 P[4];        // P^T[m][t]: m = 16mi+4lg+r, t = t_own
  #pragma unroll
  for (int mi = 0; mi < 4; ++mi) P[mi] = (f32x4){0.f,0.f,0.f,0.f};
  #pragma unroll
  for (int kk = 0; kk < 8; ++kk) {
    bf16x8 nf = *(const bf16x8*)(xrow + ((u32)(64*kk + 16*lg) ^ swz));
    #pragma unroll
    for (int mi = 0; mi < 4; ++mi) {
      bf16x8 mf = *(const bf16x8*)(gmem + (size_t)(16*mi + ll) * NC + 32*kk + 8*lg);
      P[mi] = __builtin_amdgcn_mfma_f32_16x16x32_bf16(mf, nf, P[mi], 0, 0, 0);
    }
  }
  #pragma unroll
  for (int mi = 0; mi < 4; ++mi)
    #pragma unroll
    for (int r = 0; r < 4; ++r) P[mi][r] *= rinv0;

  // ---- preload G fragments (64x64, reused 3x) ----
  bf16x8 gf[4][2];
  #pragma unroll
  for (int mi = 0; mi < 4; ++mi)
    #pragma unroll
    for (int kk = 0; kk < 2; ++kk)
      gf[mi][kk] = *(const bf16x8*)(Gb + (size_t)(16*mi + ll) * 64 + 32*kk + 8*lg);

  // ======= 3 Hopfield iterations, fully wave-private =======
  char* ab_row = smem + OFF_AC + (t_own << 7);
  float C[4][4];
  #pragma unroll
  for (int mi = 0; mi < 4; ++mi)
    #pragma unroll
    for (int r = 0; r < 4; ++r) C[mi][r] = 0.f;
  float n2 = 1.0f;

  #pragma unroll
  for (int k = 0; k < 3; ++k) {
    const float wk = (k == 0) ? 0.125f : (k == 1) ? 0.25f : 0.5f;
    float rinv = 1.0f / sqrtf(fmaxf(n2, 1e-24f));
    float sc[4][4];
    float mx = -1e30f;
    #pragma unroll
    for (int mi = 0; mi < 4; ++mi)
      #pragma unroll
      for (int r = 0; r < 4; ++r) { sc[mi][r] = P[mi][r] * rinv; mx = fmaxf(mx, sc[mi][r]); }
    mx = fmaxf(mx, __shfl_xor(mx, 16));
    mx = fmaxf(mx, __shfl_xor(mx, 32));
    float A[4][4];
    float S = 0.f;
    #pragma unroll
    for (int mi = 0; mi < 4; ++mi)
      #pragma unroll
      for (int r = 0; r < 4; ++r) { float e = __expf(sc[mi][r] - mx); A[mi][r] = e; S += e; }
    S += __shfl_xor(S, 16);
    S += __shfl_xor(S, 32);
    float sinv = 1.0f / S;
    float dPA = 0.f;
    #pragma unroll
    for (int mi = 0; mi < 4; ++mi)
      #pragma unroll
      for (int r = 0; r < 4; ++r) {
        A[mi][r] *= sinv;
        dPA += A[mi][r] * P[mi][r];
        C[mi][r] += wk * A[mi][r];
      }
    dPA += __shfl_xor(dPA, 16);
    dPA += __shfl_xor(dPA, 32);
    #pragma unroll
    for (int mi = 0; mi < 4; ++mi) {
      uint2 v; v.x = pack2(A[mi][0], A[mi][1]); v.y = pack2(A[mi][2], A[mi][3]);
      *(uint2*)(ab_row + ((u32)(32*mi + 8*lg) ^ swz)) = v;
    }
    f32x4 V[4];
    #pragma unroll
    for (int mi = 0; mi < 4; ++mi) V[mi] = (f32x4){0.f,0.f,0.f,0.f};
    #pragma unroll
    for (int kk = 0; kk < 2; ++kk) {
      bf16x8 nf = *(const bf16x8*)(ab_row + ((u32)(64*kk + 16*lg) ^ swz));
      #pragma unroll
      for (int mi = 0; mi < 4; ++mi)
        V[mi] = __builtin_amdgcn_mfma_f32_16x16x32_bf16(gf[mi][kk], nf, V[mi], 0, 0, 0);
    }
    float dVA = 0.f;
    #pragma unroll
    for (int mi = 0; mi < 4; ++mi)
      #pragma unroll
      for (int r = 0; r < 4; ++r) {
        dVA += A[mi][r] * V[mi][r];
        P[mi][r] = 0.5f * (P[mi][r] + V[mi][r]);
      }
    dVA += __shfl_xor(dVA, 16);
    dVA += __shfl_xor(dVA, 32);
    n2 = 0.25f * n2 + 0.5f * dPA + 0.25f * dVA;
  }

  // ---- C -> LDS bf16 ----
  #pragma unroll
  for (int mi = 0; mi < 4; ++mi) {
    uint2 v; v.x = pack2(C[mi][0], C[mi][1]); v.y = pack2(C[mi][2], C[mi][3]);
    *(uint2*)(ab_row + ((u32)(32*mi + 8*lg) ^ swz)) = v;
  }
  __syncthreads();   // barrier 4: C ready

  // ======= out-core: 0.125*rinv0*(Wout q) + WM*C + bout =======
  #pragma unroll
  for (int oi = 0; oi < 4; ++oi)
    #pragma unroll
    for (int ti = 0; ti < 4; ++ti) acc[oi][ti] = (f32x4){0.f,0.f,0.f,0.f};
  #pragma unroll
  for (int kk = 0; kk < 8; ++kk) {
    bf16x8 nf[4];
    #pragma unroll
    for (int ti = 0; ti < 4; ++ti) {
      int row = 16*ti + ll;
      nf[ti] = *(const bf16x8*)(smem + OFF_XZT + (row << 9)
                                + ((u32)(64*kk + 16*lg) ^ (u32)((row & 7) << 4)));
    }
    bf16x8 mf[4];
    #pragma unroll
    for (int oi = 0; oi < 4; ++oi)
      mf[oi] = *(const bf16x8*)(wout + (size_t)(64*w + 16*oi + ll) * NC + 32*kk + 8*lg);
    #pragma unroll
    for (int oi = 0; oi < 4; ++oi)
      #pragma unroll
      for (int ti = 0; ti < 4; ++ti)
        acc[oi][ti] = __builtin_amdgcn_mfma_f32_16x16x32_bf16(mf[oi], nf[ti], acc[oi][ti], 0, 0, 0);
  }
  #pragma unroll
  for (int ti = 0; ti < 4; ++ti) {
    float rv = 0.125f * RinvL[16*ti + ll];
    #pragma unroll
    for (int oi = 0; oi < 4; ++oi)
      #pragma unroll
      for (int r = 0; r < 4; ++r) acc[oi][ti][r] *= rv;
  }
  #pragma unroll
  for (int kk = 0; kk < 2; ++kk) {
    bf16x8 nf[4];
    #pragma unroll
    for (int ti = 0; ti < 4; ++ti)
      nf[ti] = *(const bf16x8*)(smem + OFF_AC + ((16*ti + ll) << 7)
                                + ((u32)(64*kk + 16*lg) ^ swz));
    bf16x8 mf[4];
    #pragma unroll
    for (int oi = 0; oi < 4; ++oi)
      mf[oi] = *(const bf16x8*)(WMb + (size_t)(64*w + 16*oi + ll) * 64 + 32*kk + 8*lg);
    #pragma unroll
    for (int oi = 0; oi < 4; ++oi)
      #pragma unroll
      for (int ti = 0; ti < 4; ++ti)
        acc[oi][ti] = __builtin_amdgcn_mfma_f32_16x16x32_bf16(mf[oi], nf[ti], acc[oi][ti], 0, 0, 0);
  }
  #pragma unroll
  for (int oi = 0; oi < 4; ++oi) {
    f32x4 bv = *(const f32x4*)&bout[64*w + 16*oi + 4*lg];
    #pragma unroll
    for (int ti = 0; ti < 4; ++ti)
      #pragma unroll
      for (int r = 0; r < 4; ++r) acc[oi][ti][r] += bv[r];
  }
  __syncthreads();   // barrier 5: region A (q^T) and AC reads done

  // ======= epilogue: per-wave LDS transpose (8KB quarter of region A), coalesced I/O =======
  {
    char* OB = smem + OFF_XZT + ((u32)w << 13);   // f32[32][64], XOR-swizzled
    #pragma unroll
    for (int h = 0; h < 2; ++h) {
      __builtin_amdgcn_sched_barrier(0);
      #pragma unroll
      for (int q = 0; q < 2; ++q) {
        int oi = 2*h + q;
        #pragma unroll
        for (int ti = 0; ti < 4; ++ti)
          #pragma unroll
          for (int r = 0; r < 4; ++r) {
            int o_loc = 16*q + 4*lg + r;
            int t = 16*ti + ll;
            *(float*)(OB + (o_loc << 8) + ((u32)(t << 2) ^ (u32)((o_loc & 7) << 4)))
                = acc[oi][ti][r];
          }
      }
      __builtin_amdgcn_sched_barrier(0);
      #pragma unroll
      for (int s = 0; s < 8; ++s) {
        int o_loc = 4*s + lg;
        int o = 64*w + 32*h + o_loc;
        f32x4 v = *(const f32x4*)(OB + (o_loc << 8)
                                  + ((u32)(16*ll) ^ (u32)((o_loc & 7) << 4)));
        float4 vx = *(const float4*)(xb + (size_t)o * NHW + 4*ll);
        float4 vo = { v[0] + vx.x, v[1] + vx.y, v[2] + vx.z, v[3] + vx.w };
        *(float4*)(ob + (size_t)o * NHW + 4*ll) = vo;
      }
    }
  }
}

extern "C" void kernel_launch(void* const* d_in, const int* in_sizes, int n_in,
                              void* d_out, int out_size, void* d_ws, size_t ws_size,
                              hipStream_t stream) {
  const float* x    = (const float*)d_in[0];
  const float* memb = (const float*)d_in[1];
  const float* Wq   = (const float*)d_in[2];
  const float* bq   = (const float*)d_in[3];
  const float* Wout = (const float*)d_in[4];
  const float* bout = (const float*)d_in[5];
  float* out = (float*)d_out;

  u16* wq_b   = (u16*)d_ws;                 // 65536
  u16* wout_b = wq_b + 65536;               // 65536
  u16* mem_b  = wq_b + 131072;              // 16384
  u16* G_b    = wq_b + 147456;              // 4096
  u16* WM_b   = wq_b + 151552;              // 16384

  hop_prep<<<98, 256, 0, stream>>>(Wq, Wout, memb, wq_b, wout_b, mem_b, G_b, WM_b);
  hop_main<<<1024, 256, 0, stream>>>(x, bq, bout, wq_b, wout_b, mem_b, G_b, WM_b, out);
}

// Round 5
// 79.470 us; speedup vs baseline: 1.4897x; 1.4897x over previous
//
#include <hip/hip_runtime.h>
#include <hip/hip_bf16.h>

typedef unsigned short u16;
typedef unsigned int   u32;
typedef __attribute__((ext_vector_type(8))) short bf16x8;
typedef __attribute__((ext_vector_type(4))) float f32x4;

#define NC  256
#define NHW 4096

// ---- LDS layout (bytes) ----
#define OFF_XZT 0        // u16[64][256] XOR-swizzled: x-tile, then q^T (token-major), then OB
#define OFF_AC  32768    // u16[64][64]  XOR-swizzled: A (per-iter, wave-private rows) then C
#define OFF_ST  40960    // f32[64][4]   ||q||^2 partials per wave
#define OFF_RI  41984    // f32[64]      rinv0 per token
#define SMEM_SZ 42240

__device__ __forceinline__ u16 f2bf_rne(float f) {
  u32 u = __float_as_uint(f);
  return (u16)((u + 0x7FFFu + ((u >> 16) & 1u)) >> 16);
}
__device__ __forceinline__ u16 f2bf(float f) {
  __hip_bfloat16 h = __float2bfloat16(f);
  return *reinterpret_cast<u16*>(&h);
}
__device__ __forceinline__ u32 pack2(float a, float b) {
  return (u32)f2bf(a) | ((u32)f2bf(b) << 16);
}

// =======================================================================
// prep: build fragment-permuted bf16 operand arrays.
// Fragment layout for 16x16x32 MFMA M-side: frag(f) lane l holds
// W[row0 + (l&15)][col0 + 8*(l>>4) .. +8], stored at [f*512 + l*8] u16.
// =======================================================================
__global__ void hop_prep(const float* __restrict__ wq_f, const float* __restrict__ wo_f,
                         const float* __restrict__ memb,
                         u16* __restrict__ wq_p, u16* __restrict__ wo_p,
                         u16* __restrict__ WM_p, u16* __restrict__ G_p,
                         u16* __restrict__ mem_p) {
  const int blk = blockIdx.x, tid = threadIdx.x;

  if (blk < 64) {   // wq_p / wo_p : one frag (8 u16) per thread
    const float* src = (blk < 32) ? wq_f : wo_f;
    u16* dst = (blk < 32) ? wq_p : wo_p;
    int f = ((blk & 31) << 8) + tid;          // 0..8191
    int l = f & 63, g = f >> 6;
    int oi = g & 3, kk = (g >> 2) & 7, w = g >> 5;
    int row = 64*w + 16*oi + (l & 15);
    int col = 32*kk + 8*(l >> 4);
    const float* s = src + (size_t)row * NC + col;
    uint4 v;
    v.x = (u32)f2bf_rne(s[0]) | ((u32)f2bf_rne(s[1]) << 16);
    v.y = (u32)f2bf_rne(s[2]) | ((u32)f2bf_rne(s[3]) << 16);
    v.z = (u32)f2bf_rne(s[4]) | ((u32)f2bf_rne(s[5]) << 16);
    v.w = (u32)f2bf_rne(s[6]) | ((u32)f2bf_rne(s[7]) << 16);
    *(uint4*)(dst + (size_t)f * 8) = v;
    return;
  }

  __shared__ float rn[64];
  if (tid < 64) {
    float ssum = 0.f;
    const float* mr = memb + tid * NC;
    for (int c = 0; c < NC; ++c) { float v = mr[c]; ssum += v * v; }
    rn[tid] = 1.0f / fmaxf(sqrtf(ssum), 1e-12f);
  }
  __syncthreads();

  if (blk < 128) {  // WM_p = Wout @ mem_norm^T, one element per thread
    int e = ((blk - 64) << 8) + tid;          // 0..16383
    int f = e >> 3, j = e & 7;
    int l = f & 63, g = f >> 6;
    int oi = g & 3, kk2 = (g >> 2) & 1, w = g >> 3;
    int row = 64*w + 16*oi + (l & 15);
    int m   = 32*kk2 + 8*(l >> 4) + j;
    const float* wr = wo_f + (size_t)row * NC;
    const float* mr = memb + (size_t)m * NC;
    float s = 0.f;
    for (int c = 0; c < NC; ++c) s += wr[c] * mr[c];
    WM_p[e] = f2bf_rne(s * rn[m]);
    return;
  }
  if (blk < 144) {  // G_p = mem_norm @ mem_norm^T, one element per thread
    int e = ((blk - 128) << 8) + tid;         // 0..4095
    int f = e >> 3, j = e & 7;
    int l = f & 63, g = f >> 6;
    int mi = g & 3, kk2 = g >> 2;
    int m  = 16*mi + (l & 15);
    int mp = 32*kk2 + 8*(l >> 4) + j;
    const float* ma = memb + (size_t)m * NC;
    const float* mb2 = memb + (size_t)mp * NC;
    float s = 0.f;
    for (int c = 0; c < NC; ++c) s += ma[c] * mb2[c];
    G_p[e] = f2bf_rne(s * rn[m] * rn[mp]);
    return;
  }
  {                 // mem_p (normalized mem bank frags): one frag per thread
    int f = ((blk - 144) << 8) + tid;         // 0..2047
    int l = f & 63, g = f >> 6;
    int mi = g & 3, kk = g >> 2;
    int row = 16*mi + (l & 15);
    int col = 32*kk + 8*(l >> 4);
    float rv = rn[row];
    const float* mr = memb + (size_t)row * NC + col;
    uint4 v;
    v.x = (u32)f2bf_rne(mr[0]*rv) | ((u32)f2bf_rne(mr[1]*rv) << 16);
    v.y = (u32)f2bf_rne(mr[2]*rv) | ((u32)f2bf_rne(mr[3]*rv) << 16);
    v.z = (u32)f2bf_rne(mr[4]*rv) | ((u32)f2bf_rne(mr[5]*rv) << 16);
    v.w = (u32)f2bf_rne(mr[6]*rv) | ((u32)f2bf_rne(mr[7]*rv) << 16);
    *(uint4*)(mem_p + (size_t)f * 8) = v;
  }
}

__device__ __forceinline__ void mfma16(const bf16x8 (&mf)[4], const bf16x8 (&nf)[4],
                                       f32x4 (&acc)[4][4]) {
  #pragma unroll
  for (int oi = 0; oi < 4; ++oi)
    #pragma unroll
    for (int ti = 0; ti < 4; ++ti)
      acc[oi][ti] = __builtin_amdgcn_mfma_f32_16x16x32_bf16(mf[oi], nf[ti], acc[oi][ti], 0, 0, 0);
}

// ---- fused main kernel: block = 64 tokens, 4 waves ----
__global__ __launch_bounds__(256, 3) void hop_main(
    const float* __restrict__ x, const float* __restrict__ bq,
    const float* __restrict__ bout, const u16* __restrict__ wq_p,
    const u16* __restrict__ wo_p, const u16* __restrict__ mem_p,
    const u16* __restrict__ G_p, const u16* __restrict__ WM_p,
    float* __restrict__ out) {
  __shared__ __align__(16) char smem[SMEM_SZ];
  float* StatR = (float*)(smem + OFF_ST);   // [64][4]
  float* RinvL = (float*)(smem + OFF_RI);   // [64]

  const int tid = threadIdx.x;
  const int w  = tid >> 6;
  const int l  = tid & 63;
  const int lg = l >> 4;
  const int ll = l & 15;
  const u32 swz = (u32)((ll & 7) << 4);

  const int bimg = blockIdx.x >> 6;
  const int t0   = (blockIdx.x & 63) * 64;
  const float* xb = x   + (size_t)bimg * NC * NHW + t0;
  float*       ob = out + (size_t)bimg * NC * NHW + t0;

  // ======= stage x-tile -> region A: bf16 token-major [t][c], XOR-swizzled =======
  {
    const int tq = tid & 15;
    const int cb = tid >> 4;
    #pragma unroll 2
    for (int j = 0; j < 8; ++j) {
      int cp = cb + 16*j;
      const float* r0 = xb + (size_t)(2*cp) * NHW + 4*tq;
      float4 a = *(const float4*)r0;
      float4 b = *(const float4*)(r0 + NHW);
      #pragma unroll
      for (int i = 0; i < 4; ++i) {
        int t = 4*tq + i;
        *(u32*)(smem + OFF_XZT + (t << 9) + (((u32)(cp << 2)) ^ (u32)((t & 7) << 4)))
            = pack2((&a.x)[i], (&b.x)[i]);
      }
    }
  }
  __syncthreads();   // barrier 1: x-tile ready

  // ======= GEMM1: q^T[o][t], wave w owns o in [64w,64w+64), pipelined trip-4 =======
  f32x4 acc[4][4];
  #pragma unroll
  for (int oi = 0; oi < 4; ++oi)
    #pragma unroll
    for (int ti = 0; ti < 4; ++ti) acc[oi][ti] = (f32x4){0.f,0.f,0.f,0.f};
  {
    const u16* wqf = wq_p + (size_t)w * 16384 + (size_t)l * 8;
    bf16x8 mfA[4], mfB[4], nfA[4], nfB[4];
    #pragma unroll
    for (int oi = 0; oi < 4; ++oi) mfA[oi] = *(const bf16x8*)(wqf + oi*512);
    #pragma unroll
    for (int ti = 0; ti < 4; ++ti) {
      int row = 16*ti + ll;
      nfA[ti] = *(const bf16x8*)(smem + OFF_XZT + (row << 9) + ((u32)(16*lg) ^ (u32)((row & 7) << 4)));
    }
    for (int kp = 0; kp < 4; ++kp) {
      const int kb = 2*kp + 1, kc = (2*kp + 2) & 7;
      const u16* pB = wqf + kb*2048;
      #pragma unroll
      for (int oi = 0; oi < 4; ++oi) mfB[oi] = *(const bf16x8*)(pB + oi*512);
      #pragma unroll
      for (int ti = 0; ti < 4; ++ti) {
        int row = 16*ti + ll;
        nfB[ti] = *(const bf16x8*)(smem + OFF_XZT + (row << 9) + ((u32)(64*kb + 16*lg) ^ (u32)((row & 7) << 4)));
      }
      mfma16(mfA, nfA, acc);
      const u16* pC = wqf + kc*2048;
      #pragma unroll
      for (int oi = 0; oi < 4; ++oi) mfA[oi] = *(const bf16x8*)(pC + oi*512);
      #pragma unroll
      for (int ti = 0; ti < 4; ++ti) {
        int row = 16*ti + ll;
        nfA[ti] = *(const bf16x8*)(smem + OFF_XZT + (row << 9) + ((u32)(64*kc + 16*lg) ^ (u32)((row & 7) << 4)));
      }
      mfma16(mfB, nfB, acc);
    }
  }
  #pragma unroll
  for (int oi = 0; oi < 4; ++oi) {
    f32x4 bv = *(const f32x4*)&bq[64*w + 16*oi + 4*lg];
    #pragma unroll
    for (int ti = 0; ti < 4; ++ti)
      #pragma unroll
      for (int r = 0; r < 4; ++r) acc[oi][ti][r] += bv[r];
  }

  // ---- ||q||^2 partials -> StatR ----
  #pragma unroll
  for (int ti = 0; ti < 4; ++ti) {
    float v = 0.f;
    #pragma unroll
    for (int oi = 0; oi < 4; ++oi)
      #pragma unroll
      for (int r = 0; r < 4; ++r) { float e = acc[oi][ti][r]; v += e*e; }
    v += __shfl_xor(v, 16);
    v += __shfl_xor(v, 32);
    if (lg == 0) StatR[(16*ti + ll)*4 + w] = v;
  }
  __syncthreads();   // barrier 2: x-tile reads done; StatR ready

  // ---- q^T -> region A (overwrite), bf16 XOR-swizzled ----
  #pragma unroll
  for (int oi = 0; oi < 4; ++oi)
    #pragma unroll
    for (int ti = 0; ti < 4; ++ti) {
      int row = 16*ti + ll;
      int colb = (64*w + 16*oi + 4*lg) << 1;
      uint2 v; v.x = pack2(acc[oi][ti][0], acc[oi][ti][1]);
               v.y = pack2(acc[oi][ti][2], acc[oi][ti][3]);
      *(uint2*)(smem + OFF_XZT + (row << 9) + ((u32)colb ^ swz)) = v;
    }
  __syncthreads();   // barrier 3: q^T ready

  const int t_own = 16*w + ll;
  float rinv0;
  {
    f32x4 p = *(const f32x4*)&StatR[t_own * 4];
    rinv0 = 1.0f / fmaxf(sqrtf(p[0] + p[1] + p[2] + p[3]), 1e-12f);
    if (lg == 0) RinvL[t_own] = rinv0;
  }

  // ======= P0 = rinv0 * (mem_norm @ q), per-wave (16 tokens), pipelined =======
  const char* xrow = smem + OFF_XZT + (t_own << 9);
  f32x4 P[4];
  #pragma unroll
  for (int mi = 0; mi < 4; ++mi) P[mi] = (f32x4){0.f,0.f,0.f,0.f};
  {
    const u16* mf0 = mem_p + (size_t)l * 8;
    bf16x8 pmA[4], pmB[4], nA, nB;
    nA = *(const bf16x8*)(xrow + ((u32)(16*lg) ^ swz));
    #pragma unroll
    for (int mi = 0; mi < 4; ++mi) pmA[mi] = *(const bf16x8*)(mf0 + mi*512);
    for (int kp = 0; kp < 4; ++kp) {
      const int kb = 2*kp + 1, kc = (2*kp + 2) & 7;
      nB = *(const bf16x8*)(xrow + ((u32)(64*kb + 16*lg) ^ swz));
      #pragma unroll
      for (int mi = 0; mi < 4; ++mi) pmB[mi] = *(const bf16x8*)(mf0 + (kb*4 + mi)*512);
      #pragma unroll
      for (int mi = 0; mi < 4; ++mi)
        P[mi] = __builtin_amdgcn_mfma_f32_16x16x32_bf16(pmA[mi], nA, P[mi], 0, 0, 0);
      nA = *(const bf16x8*)(xrow + ((u32)(64*kc + 16*lg) ^ swz));
      #pragma unroll
      for (int mi = 0; mi < 4; ++mi) pmA[mi] = *(const bf16x8*)(mf0 + (kc*4 + mi)*512);
      #pragma unroll
      for (int mi = 0; mi < 4; ++mi)
        P[mi] = __builtin_amdgcn_mfma_f32_16x16x32_bf16(pmB[mi], nB, P[mi], 0, 0, 0);
    }
  }
  #pragma unroll
  for (int mi = 0; mi < 4; ++mi)
    #pragma unroll
    for (int r = 0; r < 4; ++r) P[mi][r] *= rinv0;

  // ---- preload G fragments (coalesced, reused 3x) ----
  bf16x8 gf[4][2];
  #pragma unroll
  for (int mi = 0; mi < 4; ++mi)
    #pragma unroll
    for (int kk2 = 0; kk2 < 2; ++kk2)
      gf[mi][kk2] = *(const bf16x8*)(G_p + (size_t)((kk2*4 + mi)*512) + (size_t)l*8);

  // ======= 3 Hopfield iterations, fully wave-private =======
  char* ab_row = smem + OFF_AC + (t_own << 7);
  float C[4][4];
  #pragma unroll
  for (int mi = 0; mi < 4; ++mi)
    #pragma unroll
    for (int r = 0; r < 4; ++r) C[mi][r] = 0.f;
  float n2 = 1.0f;

  #pragma unroll
  for (int k = 0; k < 3; ++k) {
    const float wk = (k == 0) ? 0.125f : (k == 1) ? 0.25f : 0.5f;
    float rinv = 1.0f / sqrtf(fmaxf(n2, 1e-24f));
    float sc[4][4];
    float mx = -1e30f;
    #pragma unroll
    for (int mi = 0; mi < 4; ++mi)
      #pragma unroll
      for (int r = 0; r < 4; ++r) { sc[mi][r] = P[mi][r] * rinv; mx = fmaxf(mx, sc[mi][r]); }
    mx = fmaxf(mx, __shfl_xor(mx, 16));
    mx = fmaxf(mx, __shfl_xor(mx, 32));
    float A[4][4];
    float S = 0.f;
    #pragma unroll
    for (int mi = 0; mi < 4; ++mi)
      #pragma unroll
      for (int r = 0; r < 4; ++r) { float e = __expf(sc[mi][r] - mx); A[mi][r] = e; S += e; }
    S += __shfl_xor(S, 16);
    S += __shfl_xor(S, 32);
    float sinv = 1.0f / S;
    float dPA = 0.f;
    #pragma unroll
    for (int mi = 0; mi < 4; ++mi)
      #pragma unroll
      for (int r = 0; r < 4; ++r) {
        A[mi][r] *= sinv;
        dPA += A[mi][r] * P[mi][r];
        C[mi][r] += wk * A[mi][r];
      }
    dPA += __shfl_xor(dPA, 16);
    dPA += __shfl_xor(dPA, 32);
    #pragma unroll
    for (int mi = 0; mi < 4; ++mi) {
      uint2 v; v.x = pack2(A[mi][0], A[mi][1]); v.y = pack2(A[mi][2], A[mi][3]);
      *(uint2*)(ab_row + ((u32)(32*mi + 8*lg) ^ swz)) = v;
    }
    f32x4 V[4];
    #pragma unroll
    for (int mi = 0; mi < 4; ++mi) V[mi] = (f32x4){0.f,0.f,0.f,0.f};
    #pragma unroll
    for (int kk2 = 0; kk2 < 2; ++kk2) {
      bf16x8 nf = *(const bf16x8*)(ab_row + ((u32)(64*kk2 + 16*lg) ^ swz));
      #pragma unroll
      for (int mi = 0; mi < 4; ++mi)
        V[mi] = __builtin_amdgcn_mfma_f32_16x16x32_bf16(gf[mi][kk2], nf, V[mi], 0, 0, 0);
    }
    float dVA = 0.f;
    #pragma unroll
    for (int mi = 0; mi < 4; ++mi)
      #pragma unroll
      for (int r = 0; r < 4; ++r) {
        dVA += A[mi][r] * V[mi][r];
        P[mi][r] = 0.5f * (P[mi][r] + V[mi][r]);
      }
    dVA += __shfl_xor(dVA, 16);
    dVA += __shfl_xor(dVA, 32);
    n2 = 0.25f * n2 + 0.5f * dPA + 0.25f * dVA;
  }

  // ---- C -> LDS bf16 ----
  #pragma unroll
  for (int mi = 0; mi < 4; ++mi) {
    uint2 v; v.x = pack2(C[mi][0], C[mi][1]); v.y = pack2(C[mi][2], C[mi][3]);
    *(uint2*)(ab_row + ((u32)(32*mi + 8*lg) ^ swz)) = v;
  }
  __syncthreads();   // barrier 4: C ready

  // ======= out-core: 0.125*rinv0*(Wout q) + WM*C + bout =======
  #pragma unroll
  for (int oi = 0; oi < 4; ++oi)
    #pragma unroll
    for (int ti = 0; ti < 4; ++ti) acc[oi][ti] = (f32x4){0.f,0.f,0.f,0.f};
  {
    const u16* wof = wo_p + (size_t)w * 16384 + (size_t)l * 8;
    bf16x8 mfA[4], mfB[4], nfA[4], nfB[4];
    #pragma unroll
    for (int oi = 0; oi < 4; ++oi) mfA[oi] = *(const bf16x8*)(wof + oi*512);
    #pragma unroll
    for (int ti = 0; ti < 4; ++ti) {
      int row = 16*ti + ll;
      nfA[ti] = *(const bf16x8*)(smem + OFF_XZT + (row << 9) + ((u32)(16*lg) ^ (u32)((row & 7) << 4)));
    }
    for (int kp = 0; kp < 4; ++kp) {
      const int kb = 2*kp + 1, kc = (2*kp + 2) & 7;
      const u16* pB = wof + kb*2048;
      #pragma unroll
      for (int oi = 0; oi < 4; ++oi) mfB[oi] = *(const bf16x8*)(pB + oi*512);
      #pragma unroll
      for (int ti = 0; ti < 4; ++ti) {
        int row = 16*ti + ll;
        nfB[ti] = *(const bf16x8*)(smem + OFF_XZT + (row << 9) + ((u32)(64*kb + 16*lg) ^ (u32)((row & 7) << 4)));
      }
      mfma16(mfA, nfA, acc);
      const u16* pC = wof + kc*2048;
      #pragma unroll
      for (int oi = 0; oi < 4; ++oi) mfA[oi] = *(const bf16x8*)(pC + oi*512);
      #pragma unroll
      for (int ti = 0; ti < 4; ++ti) {
        int row = 16*ti + ll;
        nfA[ti] = *(const bf16x8*)(smem + OFF_XZT + (row << 9) + ((u32)(64*kc + 16*lg) ^ (u32)((row & 7) << 4)));
      }
      mfma16(mfB, nfB, acc);
    }
  }
  #pragma unroll
  for (int ti = 0; ti < 4; ++ti) {
    float rv = 0.125f * RinvL[16*ti + ll];
    #pragma unroll
    for (int oi = 0; oi < 4; ++oi)
      #pragma unroll
      for (int r = 0; r < 4; ++r) acc[oi][ti][r] *= rv;
  }
  #pragma unroll
  for (int kk2 = 0; kk2 < 2; ++kk2) {
    bf16x8 wmf[4], nfc[4];
    #pragma unroll
    for (int oi = 0; oi < 4; ++oi)
      wmf[oi] = *(const bf16x8*)(WM_p + (size_t)(((w*2 + kk2)*4 + oi)*512) + (size_t)l*8);
    #pragma unroll
    for (int ti = 0; ti < 4; ++ti)
      nfc[ti] = *(const bf16x8*)(smem + OFF_AC + ((16*ti + ll) << 7) + ((u32)(64*kk2 + 16*lg) ^ swz));
    mfma16(wmf, nfc, acc);
  }
  #pragma unroll
  for (int oi = 0; oi < 4; ++oi) {
    f32x4 bv = *(const f32x4*)&bout[64*w + 16*oi + 4*lg];
    #pragma unroll
    for (int ti = 0; ti < 4; ++ti)
      #pragma unroll
      for (int r = 0; r < 4; ++r) acc[oi][ti][r] += bv[r];
  }
  __syncthreads();   // barrier 5: region A and AC reads done

  // ======= epilogue: per-wave LDS transpose, coalesced I/O =======
  {
    char* OB = smem + OFF_XZT + ((u32)w << 13);   // f32[32][64], XOR-swizzled
    #pragma unroll
    for (int h = 0; h < 2; ++h) {
      __builtin_amdgcn_sched_barrier(0);
      #pragma unroll
      for (int q = 0; q < 2; ++q) {
        int oi = 2*h + q;
        #pragma unroll
        for (int ti = 0; ti < 4; ++ti)
          #pragma unroll
          for (int r = 0; r < 4; ++r) {
            int o_loc = 16*q + 4*lg + r;
            int t = 16*ti + ll;
            *(float*)(OB + (o_loc << 8) + ((u32)(t << 2) ^ (u32)((o_loc & 7) << 4)))
                = acc[oi][ti][r];
          }
      }
      __builtin_amdgcn_sched_barrier(0);
      #pragma unroll
      for (int s = 0; s < 8; ++s) {
        int o_loc = 4*s + lg;
        int o = 64*w + 32*h + o_loc;
        f32x4 v = *(const f32x4*)(OB + (o_loc << 8)
                                  + ((u32)(16*ll) ^ (u32)((o_loc & 7) << 4)));
        float4 vx = *(const float4*)(xb + (size_t)o * NHW + 4*ll);
        float4 vo = { v[0] + vx.x, v[1] + vx.y, v[2] + vx.z, v[3] + vx.w };
        *(float4*)(ob + (size_t)o * NHW + 4*ll) = vo;
      }
    }
  }
}

extern "C" void kernel_launch(void* const* d_in, const int* in_sizes, int n_in,
                              void* d_out, int out_size, void* d_ws, size_t ws_size,
                              hipStream_t stream) {
  const float* x    = (const float*)d_in[0];
  const float* memb = (const float*)d_in[1];
  const float* Wq   = (const float*)d_in[2];
  const float* bq   = (const float*)d_in[3];
  const float* Wout = (const float*)d_in[4];
  const float* bout = (const float*)d_in[5];
  float* out = (float*)d_out;

  u16* wq_p  = (u16*)d_ws;            // 65536 u16
  u16* wo_p  = wq_p + 65536;          // 65536
  u16* WM_p  = wq_p + 131072;         // 16384
  u16* G_p   = wq_p + 147456;         // 4096
  u16* mem_p = wq_p + 151552;         // 16384

  hop_prep<<<152, 256, 0, stream>>>(Wq, Wout, memb, wq_p, wo_p, WM_p, G_p, mem_p);
  hop_main<<<1024, 256, 0, stream>>>(x, bq, bout, wq_p, wo_p, mem_p, G_p, WM_p, out);
}